// Round 8
// baseline (190.769 us; speedup 1.0000x reference)
//
#include <hip/hip_runtime.h>
#include <math.h>

#define NT 2048       // tokens (B*S)
#define TSLOTS 4096   // token-slots (NT*K)
#define HID 512
#define INTER 2048
#define NE 8
#define TM 128        // row-tile (bucket alignment)
#define BKG 64        // k-tile
#define MAXTILES 40   // sum ceil(cnt_e/128) <= 4096/128 + 8
#define PSLOTS 5120   // padded slot capacity (4096 + 8*128)
#define KZ2 4         // gemm2 K-split

// ---------------- workspace layout (bytes) ----------------
#define WS_HMID      0          // PSLOTS*INTER ushort = 20971520
#define WS_PROBS     0          // NT*NE floats (dead after plan)
#define WS_TOPIDX    65536      // TSLOTS ints  (dead after plan)
#define WS_TOPW      81920      // TSLOTS floats (dead after plan)
#define WS_TILE_E    20971520
#define WS_TILE_B    20972032
#define WS_TILE_V    20972544
#define WS_PERM      20973056   // PSLOTS ints
#define WS_PW        20993536   // PSLOTS floats
#define WS_ISLOT     21014016   // TSLOTS ints
#define WS_XB        21030400   // NT*HID ushort = 2097152
#define WS_W1T       23127552   // 16777216
#define WS_W2T       39904768   // 16777216
#define WS_Y         56681984   // KZ2 * PSLOTS*HID ushort = 20971520 (end ~77.7MB)

typedef __attribute__((ext_vector_type(8))) short bf16x8;
typedef __attribute__((ext_vector_type(4))) float f32x4;
typedef __attribute__((ext_vector_type(8))) unsigned short ushort8;

__device__ __forceinline__ unsigned short f2bf(float f) {
    union { float f; unsigned u; } v; v.f = f;
    unsigned r = v.u + 0x7FFF + ((v.u >> 16) & 1);   // RNE
    return (unsigned short)(r >> 16);
}
__device__ __forceinline__ float bf2f(unsigned short b) {
    union { unsigned u; float f; } v; v.u = ((unsigned)b) << 16;
    return v.f;
}

__device__ __forceinline__ void gload16(const void* g, void* l) {
    __builtin_amdgcn_global_load_lds(
        (const __attribute__((address_space(1))) unsigned int*)g,
        (__attribute__((address_space(3))) unsigned int*)l, 16, 0, 0);
}

// gelu_tanh(x) == x * sigmoid(2*0.7978845608*(x + 0.044715 x^3))  (exact identity)
__device__ __forceinline__ float gelu_fast(float x) {
    float t = 1.5957691f * x + 0.0713548f * x * x * x;
    return x / (1.0f + __expf(-t));
}

// ======== router + bf16 convert: 4 tokens per 256-thread block ====
__global__ __launch_bounds__(256) void route_k(
    const float* __restrict__ hs, const float* __restrict__ wr,
    const float* __restrict__ br,
    unsigned short* __restrict__ xb,
    float* __restrict__ probs, int* __restrict__ topidx, float* __restrict__ topw)
{
    int tid = threadIdx.x;
    int lane = tid & 63, wave = tid >> 6;
    int t = blockIdx.x * 4 + wave;
    const float* x = hs + (size_t)t * HID + lane * 8;
    float4 v0 = *(const float4*)x;
    float4 v1 = *(const float4*)(x + 4);

    ushort8 ob;
    ob[0] = f2bf(v0.x); ob[1] = f2bf(v0.y); ob[2] = f2bf(v0.z); ob[3] = f2bf(v0.w);
    ob[4] = f2bf(v1.x); ob[5] = f2bf(v1.y); ob[6] = f2bf(v1.z); ob[7] = f2bf(v1.w);
    *(ushort8*)(xb + (size_t)t * HID + lane * 8) = ob;

    float xv[8] = {v0.x, v0.y, v0.z, v0.w, v1.x, v1.y, v1.z, v1.w};
    float acc[NE];
#pragma unroll
    for (int e = 0; e < NE; e++) acc[e] = 0.0f;
    const float* w = wr + (size_t)lane * 8 * NE;
#pragma unroll
    for (int j = 0; j < 8; j++) {
        float4 wa = *(const float4*)(w + j * NE);
        float4 wb = *(const float4*)(w + j * NE + 4);
        acc[0] += xv[j] * wa.x; acc[1] += xv[j] * wa.y;
        acc[2] += xv[j] * wa.z; acc[3] += xv[j] * wa.w;
        acc[4] += xv[j] * wb.x; acc[5] += xv[j] * wb.y;
        acc[6] += xv[j] * wb.z; acc[7] += xv[j] * wb.w;
    }
#pragma unroll
    for (int off = 32; off > 0; off >>= 1) {
#pragma unroll
        for (int e = 0; e < NE; e++) acc[e] += __shfl_down(acc[e], off);
    }
    if (lane == 0) {
        float l[NE], p[NE];
        float m = -1e30f;
#pragma unroll
        for (int e = 0; e < NE; e++) { l[e] = acc[e] + br[e]; m = fmaxf(m, l[e]); }
        float s = 0.0f;
#pragma unroll
        for (int e = 0; e < NE; e++) { p[e] = expf(l[e] - m); s += p[e]; }
        float inv = 1.0f / s;
#pragma unroll
        for (int e = 0; e < NE; e++) { p[e] *= inv; probs[(size_t)t * NE + e] = p[e]; }
        int i1 = 0;
#pragma unroll
        for (int e = 1; e < NE; e++) if (p[e] > p[i1]) i1 = e;
        int i2 = (i1 == 0) ? 1 : 0;
#pragma unroll
        for (int e = 0; e < NE; e++) if (e != i1 && p[e] > p[i2]) i2 = e;
        float denom = 1.0f / (p[i1] + p[i2]);
        topidx[2 * t]     = i1;
        topidx[2 * t + 1] = i2;
        topw[2 * t]       = p[i1] * denom;
        topw[2 * t + 1]   = p[i2] * denom;
    }
}

// ======== transpose+plan: block 0 = plan (runs concurrently with transposes) =
__global__ __launch_bounds__(256) void tp_k(
    const float* __restrict__ w1, const float* __restrict__ w2,
    unsigned short* __restrict__ w1t, unsigned short* __restrict__ w2t,
    const float* __restrict__ probs, const int* __restrict__ topidx,
    const float* __restrict__ topw,
    int* __restrict__ tile_e, int* __restrict__ tile_b, int* __restrict__ tile_v,
    int* __restrict__ perm, float* __restrict__ pw, int* __restrict__ islot,
    float* __restrict__ loss_out)
{
    int tid = threadIdx.x;
    if (blockIdx.x == 0) {
        // ---- plan: reduce + tile map + loss + scatter ----
        int lane = tid & 63, wave = tid >> 6;
        float ps[NE];
        int c[NE];
#pragma unroll
        for (int e = 0; e < NE; e++) { ps[e] = 0.0f; c[e] = 0; }
        for (int t = tid; t < NT; t += 256) {
            float4 p0 = *(const float4*)&probs[(size_t)t * NE];
            float4 p1 = *(const float4*)&probs[(size_t)t * NE + 4];
            ps[0] += p0.x; ps[1] += p0.y; ps[2] += p0.z; ps[3] += p0.w;
            ps[4] += p1.x; ps[5] += p1.y; ps[6] += p1.z; ps[7] += p1.w;
        }
        for (int t = tid; t < TSLOTS; t += 256) c[topidx[t]]++;
#pragma unroll
        for (int off = 32; off > 0; off >>= 1) {
#pragma unroll
            for (int e = 0; e < NE; e++) {
                ps[e] += __shfl_down(ps[e], off);
                c[e]  += __shfl_down(c[e], off);
            }
        }
        __shared__ float sps[4][NE];
        __shared__ int sc[4][NE];
        __shared__ int scur[NE], sbase[NE], scnt[NE], spref[NE + 1];
        if (lane == 0) {
#pragma unroll
            for (int e = 0; e < NE; e++) { sps[wave][e] = ps[e]; sc[wave][e] = c[e]; }
        }
        __syncthreads();
        if (tid == 0) {
            float loss = 0.0f;
            int b = 0, tp = 0;
            for (int e = 0; e < NE; e++) {
                float pse = sps[0][e] + sps[1][e] + sps[2][e] + sps[3][e];
                int ce = sc[0][e] + sc[1][e] + sc[2][e] + sc[3][e];
                loss += ((float)ce / (float)TSLOTS) * (pse / (float)NT);
                int nt = (ce + TM - 1) / TM;
                sbase[e] = b; scnt[e] = ce; scur[e] = b; spref[e] = tp;
                tp += nt;
                b += nt * TM;
            }
            spref[NE] = tp;
            loss_out[0] = 0.01f * (float)NE * loss;
        }
        __syncthreads();
        for (int tx = tid; tx < MAXTILES; tx += 256) {
            if (tx >= spref[NE]) { tile_e[tx] = -1; continue; }
            int e = 0;
            while (tx >= spref[e + 1]) e++;
            int i = tx - spref[e];
            tile_e[tx] = e;
            tile_b[tx] = sbase[e] + i * TM;
            int v = scnt[e] - i * TM;
            tile_v[tx] = v > TM ? TM : v;
        }
        __syncthreads();
        for (int t = tid; t < TSLOTS; t += 256) {
            int e = topidx[t];
            int p = atomicAdd(&scur[e], 1);
            perm[p] = t;
            pw[p] = topw[t];
            islot[t] = p;
        }
        return;
    }

    // ---- weight transpose+convert: 32x32 tiles ----
    __shared__ float T[32][33];
    int t = blockIdx.x - 1;
    const float* src;
    unsigned short* dst;
    int K, N, n0, k0;
    if (t < 8192) {            // w1: [e][K=512][N=2048] -> w1t [e][N][K]
        int e = t >> 10, rem = t & 1023;
        n0 = (rem & 63) * 32; k0 = (rem >> 6) * 32;
        src = w1 + (size_t)e * HID * INTER;
        dst = w1t + (size_t)e * INTER * HID;
        K = HID; N = INTER;
    } else {                   // w2: [e][K=2048][N=512] -> w2t [e][N][K]
        t -= 8192;
        int e = t >> 10, rem = t & 1023;
        n0 = (rem & 15) * 32; k0 = (rem >> 4) * 32;
        src = w2 + (size_t)e * INTER * HID;
        dst = w2t + (size_t)e * HID * INTER;
        K = INTER; N = HID;
    }
    int r = tid >> 3, c4 = (tid & 7) * 4;
    float4 v = *(const float4*)(src + (size_t)(k0 + r) * N + n0 + c4);
    T[r][c4 + 0] = v.x; T[r][c4 + 1] = v.y; T[r][c4 + 2] = v.z; T[r][c4 + 3] = v.w;
    __syncthreads();
    ushort4 o;
    o.x = f2bf(T[c4 + 0][r]); o.y = f2bf(T[c4 + 1][r]);
    o.z = f2bf(T[c4 + 2][r]); o.w = f2bf(T[c4 + 3][r]);
    *(ushort4*)(dst + (size_t)(n0 + r) * K + k0 + c4) = o;
}

// ======== grouped MFMA GEMM1: 128x128 tile, 4x4 acc, BK=64, swizzled ========
// mfma(bfr, af, acc) -> C^T layout: per reg-quad 4 consecutive n (vector epi).
__global__ __launch_bounds__(256) void gemm1_k(
    const unsigned short* __restrict__ xb, const unsigned short* __restrict__ w1t,
    const float* __restrict__ b1,
    const int* __restrict__ tile_e, const int* __restrict__ tile_b,
    const int* __restrict__ tile_v, const int* __restrict__ perm,
    unsigned short* __restrict__ hmid)
{
    int tt = blockIdx.y;
    int e = tile_e[tt];
    if (e < 0) return;
    int p0 = tile_b[tt], nv = tile_v[tt];
    int n0 = blockIdx.x * 128;

    __shared__ unsigned short As[128 * 64];   // 16 KB
    __shared__ unsigned short Bs[128 * 64];   // 16 KB

    int tid = threadIdx.x;
    int lane = tid & 63, wave = tid >> 6;
    int wm = (wave >> 1) * 64, wn = (wave & 1) * 64;

    // staging: granule f = tid + i*256; row = f>>3 = rb + i*32, slot = tid&7.
    // source granule g = slot ^ (row&7); row&7 invariant across i (32%8==0).
    int rb = tid >> 3;
    int g = (tid & 7) ^ (rb & 7);
    const unsigned short* ap[4];
    const unsigned short* bp[4];
    const unsigned short* bbase = w1t + (size_t)e * INTER * HID;
#pragma unroll
    for (int i = 0; i < 4; i++) {
        int r = rb + i * 32;
        int tok = perm[p0 + ((r < nv) ? r : 0)] >> 1;
        ap[i] = xb + (size_t)tok * HID + g * 8;
        bp[i] = bbase + (size_t)(n0 + r) * HID + g * 8;
    }

    f32x4 acc[4][4] = {};
    int fm = lane & 15, fq = lane >> 4;

    for (int k0 = 0; k0 < HID; k0 += BKG) {
        __syncthreads();
#pragma unroll
        for (int i = 0; i < 4; i++) gload16(ap[i] + k0, (void*)(As + (tid + i * 256) * 8));
#pragma unroll
        for (int i = 0; i < 4; i++) gload16(bp[i] + k0, (void*)(Bs + (tid + i * 256) * 8));
        __syncthreads();
#pragma unroll
        for (int kk = 0; kk < 2; kk++) {
            bf16x8 af[4], bfr[4];
#pragma unroll
            for (int mt = 0; mt < 4; mt++) {
                int R = wm + mt * 16 + fm;
                int G = (kk * 4 + fq) ^ (R & 7);
                af[mt] = *(const bf16x8*)&As[R * 64 + G * 8];
            }
#pragma unroll
            for (int nt = 0; nt < 4; nt++) {
                int R = wn + nt * 16 + fm;
                int G = (kk * 4 + fq) ^ (R & 7);
                bfr[nt] = *(const bf16x8*)&Bs[R * 64 + G * 8];
            }
#pragma unroll
            for (int mt = 0; mt < 4; mt++)
#pragma unroll
                for (int nt = 0; nt < 4; nt++)
                    acc[mt][nt] = __builtin_amdgcn_mfma_f32_16x16x32_bf16(
                        bfr[nt], af[mt], acc[mt][nt], 0, 0, 0);
        }
    }

    // epilogue: row(n) = quad*4+reg, col(m) = lane&15 (operand-swapped C^T)
    int cm = lane & 15, qn = (lane >> 4) * 4;
#pragma unroll
    for (int mt = 0; mt < 4; mt++) {
        int m = wm + mt * 16 + cm;
        size_t rowoff = (size_t)(p0 + m) * INTER;
#pragma unroll
        for (int nt = 0; nt < 4; nt++) {
            int nb = n0 + wn + nt * 16 + qn;
            float4 bb = *(const float4*)(b1 + e * INTER + nb);
            ushort4 o;
            o.x = f2bf(gelu_fast(acc[mt][nt][0] + bb.x));
            o.y = f2bf(gelu_fast(acc[mt][nt][1] + bb.y));
            o.z = f2bf(gelu_fast(acc[mt][nt][2] + bb.z));
            o.w = f2bf(gelu_fast(acc[mt][nt][3] + bb.w));
            *(ushort4*)(hmid + rowoff + nb) = o;
        }
    }
}

// ======== grouped MFMA GEMM2: 128x128 tile, 4x4 acc, kz=4, swizzled =========
__global__ __launch_bounds__(256) void gemm2_k(
    const unsigned short* __restrict__ hmid, const unsigned short* __restrict__ w2t,
    const float* __restrict__ b2,
    const int* __restrict__ tile_e, const int* __restrict__ tile_b,
    unsigned short* __restrict__ y)
{
    int tt = blockIdx.y;
    int e = tile_e[tt];
    if (e < 0) return;
    int p0 = tile_b[tt];
    int n0 = blockIdx.x * 128;
    int kz = blockIdx.z;
    int kbeg = kz * (INTER / KZ2), kend = kbeg + INTER / KZ2;
    unsigned short* yk = y + (size_t)kz * PSLOTS * HID;

    __shared__ unsigned short As[128 * 64];   // 16 KB
    __shared__ unsigned short Bs[128 * 64];   // 16 KB

    int tid = threadIdx.x;
    int lane = tid & 63, wave = tid >> 6;
    int wm = (wave >> 1) * 64, wn = (wave & 1) * 64;

    int rb = tid >> 3;
    int g = (tid & 7) ^ (rb & 7);
    const unsigned short* ap[4];
    const unsigned short* bp[4];
    const unsigned short* bbase = w2t + (size_t)e * HID * INTER;
#pragma unroll
    for (int i = 0; i < 4; i++) {
        int r = rb + i * 32;
        ap[i] = hmid + (size_t)(p0 + r) * INTER + g * 8;
        bp[i] = bbase + (size_t)(n0 + r) * INTER + g * 8;
    }

    f32x4 acc[4][4] = {};
    int fm = lane & 15, fq = lane >> 4;

    for (int k0 = kbeg; k0 < kend; k0 += BKG) {
        __syncthreads();
#pragma unroll
        for (int i = 0; i < 4; i++) gload16(ap[i] + k0, (void*)(As + (tid + i * 256) * 8));
#pragma unroll
        for (int i = 0; i < 4; i++) gload16(bp[i] + k0, (void*)(Bs + (tid + i * 256) * 8));
        __syncthreads();
#pragma unroll
        for (int kk = 0; kk < 2; kk++) {
            bf16x8 af[4], bfr[4];
#pragma unroll
            for (int mt = 0; mt < 4; mt++) {
                int R = wm + mt * 16 + fm;
                int G = (kk * 4 + fq) ^ (R & 7);
                af[mt] = *(const bf16x8*)&As[R * 64 + G * 8];
            }
#pragma unroll
            for (int nt = 0; nt < 4; nt++) {
                int R = wn + nt * 16 + fm;
                int G = (kk * 4 + fq) ^ (R & 7);
                bfr[nt] = *(const bf16x8*)&Bs[R * 64 + G * 8];
            }
#pragma unroll
            for (int mt = 0; mt < 4; mt++)
#pragma unroll
                for (int nt = 0; nt < 4; nt++)
                    acc[mt][nt] = __builtin_amdgcn_mfma_f32_16x16x32_bf16(
                        bfr[nt], af[mt], acc[mt][nt], 0, 0, 0);
        }
    }

    int cm = lane & 15, qn = (lane >> 4) * 4;
#pragma unroll
    for (int mt = 0; mt < 4; mt++) {
        int m = wm + mt * 16 + cm;
        size_t rowoff = (size_t)(p0 + m) * HID;
#pragma unroll
        for (int nt = 0; nt < 4; nt++) {
            int nb = n0 + wn + nt * 16 + qn;
            float4 bb = (kz == 0) ? *(const float4*)(b2 + e * HID + nb)
                                  : float4{0.0f, 0.0f, 0.0f, 0.0f};
            ushort4 o;
            o.x = f2bf(acc[mt][nt][0] + bb.x);
            o.y = f2bf(acc[mt][nt][1] + bb.y);
            o.z = f2bf(acc[mt][nt][2] + bb.z);
            o.w = f2bf(acc[mt][nt][3] + bb.w);
            *(ushort4*)(yk + rowoff + nb) = o;
        }
    }
}

// ======== combine: out = hs + wA*sum_z y_z[pA] + wB*sum_z y_z[pB] ============
__global__ __launch_bounds__(256) void combine_k(
    const float* __restrict__ hs, const unsigned short* __restrict__ y,
    const int* __restrict__ islot, const float* __restrict__ pw,
    float* __restrict__ out)
{
    int tid = threadIdx.x;
    int lane = tid & 63, wave = tid >> 6;
    int t = blockIdx.x * 4 + wave;
    int pA = islot[2 * t], pB = islot[2 * t + 1];
    float wA = pw[pA], wB = pw[pB];
    int c = lane * 8;
    float oa[8] = {}, ob[8] = {};
#pragma unroll
    for (int z = 0; z < KZ2; z++) {
        ushort8 a = *(const ushort8*)(y + (size_t)z * PSLOTS * HID + (size_t)pA * HID + c);
        ushort8 b = *(const ushort8*)(y + (size_t)z * PSLOTS * HID + (size_t)pB * HID + c);
#pragma unroll
        for (int j = 0; j < 8; j++) { oa[j] += bf2f(a[j]); ob[j] += bf2f(b[j]); }
    }
    const float* h = hs + (size_t)t * HID + c;
    float4 h0 = *(const float4*)h;
    float4 h1 = *(const float4*)(h + 4);
    float4 r0 = {wA * oa[0] + wB * ob[0] + h0.x, wA * oa[1] + wB * ob[1] + h0.y,
                 wA * oa[2] + wB * ob[2] + h0.z, wA * oa[3] + wB * ob[3] + h0.w};
    float4 r1 = {wA * oa[4] + wB * ob[4] + h1.x, wA * oa[5] + wB * ob[5] + h1.y,
                 wA * oa[6] + wB * ob[6] + h1.z, wA * oa[7] + wB * ob[7] + h1.w};
    float* op = out + (size_t)t * HID + c;
    *(float4*)op = r0;
    *(float4*)(op + 4) = r1;
}

extern "C" void kernel_launch(void* const* d_in, const int* in_sizes, int n_in,
                              void* d_out, int out_size, void* d_ws, size_t ws_size,
                              hipStream_t stream) {
    const float* hs = (const float*)d_in[0];
    const float* wr = (const float*)d_in[1];
    const float* br = (const float*)d_in[2];
    const float* w1 = (const float*)d_in[3];
    const float* b1 = (const float*)d_in[4];
    const float* w2 = (const float*)d_in[5];
    const float* b2 = (const float*)d_in[6];
    float* out = (float*)d_out;

    char* ws = (char*)d_ws;
    float* probs           = (float*)(ws + WS_PROBS);
    int*   topidx          = (int*)(ws + WS_TOPIDX);
    float* topw            = (float*)(ws + WS_TOPW);
    int*   tile_e          = (int*)(ws + WS_TILE_E);
    int*   tile_b          = (int*)(ws + WS_TILE_B);
    int*   tile_v          = (int*)(ws + WS_TILE_V);
    int*   perm            = (int*)(ws + WS_PERM);
    float* pw              = (float*)(ws + WS_PW);
    int*   islot           = (int*)(ws + WS_ISLOT);
    unsigned short* xb     = (unsigned short*)(ws + WS_XB);
    unsigned short* w1t    = (unsigned short*)(ws + WS_W1T);
    unsigned short* w2t    = (unsigned short*)(ws + WS_W2T);
    unsigned short* hmid   = (unsigned short*)(ws + WS_HMID);
    unsigned short* y      = (unsigned short*)(ws + WS_Y);

    route_k<<<NT / 4, 256, 0, stream>>>(hs, wr, br, xb, probs, topidx, topw);
    tp_k<<<1 + 16384, 256, 0, stream>>>(w1, w2, w1t, w2t, probs, topidx, topw,
                                        tile_e, tile_b, tile_v, perm, pw, islot,
                                        out + (size_t)NT * HID);
    gemm1_k<<<dim3(INTER / 128, MAXTILES), 256, 0, stream>>>(
        xb, w1t, b1, tile_e, tile_b, tile_v, perm, hmid);
    gemm2_k<<<dim3(HID / 128, MAXTILES, KZ2), 256, 0, stream>>>(
        hmid, w2t, b2, tile_e, tile_b, y);
    combine_k<<<NT / 4, 256, 0, stream>>>(hs, y, islot, pw, out);
}